// Round 6
// baseline (206.767 us; speedup 1.0000x reference)
//
#include <hip/hip_runtime.h>
#include <hip/hip_bf16.h>
#include <stdint.h>

typedef _Float16 f16;
typedef _Float16 f16x8 __attribute__((ext_vector_type(8)));
typedef float f32x4 __attribute__((ext_vector_type(4)));

#define AS1 __attribute__((address_space(1)))
#define AS3 __attribute__((address_space(3)))

// ---------------------------------------------------------------------------
// Transpose + fp32->fp16 convert:  src [R][C] f32  ->  dst [C][R] f16
// ---------------------------------------------------------------------------
__global__ __launch_bounds__(256) void tr_cvt_kernel(
    const float* __restrict__ src, f16* __restrict__ dst, int R, int C)
{
    __shared__ float tile[64][65];
    const int b = blockIdx.z;
    src += (size_t)b * R * C;
    dst += (size_t)b * R * C;
    const int c0 = blockIdx.x * 64;
    const int r0 = blockIdx.y * 64;
    const int t = threadIdx.x;
    {
        const int cc = (t & 15) * 4;
        const int rr = t >> 4;
#pragma unroll
        for (int p = 0; p < 4; ++p) {
            const int r = rr + p * 16;
            const float4 v = *(const float4*)(src + (size_t)(r0 + r) * C + c0 + cc);
            tile[r][cc + 0] = v.x; tile[r][cc + 1] = v.y;
            tile[r][cc + 2] = v.z; tile[r][cc + 3] = v.w;
        }
    }
    __syncthreads();
    {
        const int rq = (t & 15) * 4;
        const int cp = t >> 4;
#pragma unroll
        for (int p = 0; p < 4; ++p) {
            const int c = cp + p * 16;
            ushort4 o;
            f16 h0 = (f16)tile[rq + 0][c];
            f16 h1 = (f16)tile[rq + 1][c];
            f16 h2 = (f16)tile[rq + 2][c];
            f16 h3 = (f16)tile[rq + 3][c];
            o.x = __builtin_bit_cast(unsigned short, h0);
            o.y = __builtin_bit_cast(unsigned short, h1);
            o.z = __builtin_bit_cast(unsigned short, h2);
            o.w = __builtin_bit_cast(unsigned short, h3);
            *(ushort4*)(dst + (size_t)(c0 + c) * R + r0 + rq) = o;
        }
    }
}

// ---------------------------------------------------------------------------
// Deep-pipelined 256x256 GEMM core, BK=32, 4-slot LDS ring (128 KB total),
// staging 3 K-tiles ahead, per-tile 2 phases of 16 MFMA, counted vmcnt(8)
// (never drains mid-loop), raw s_barrier, setprio around MFMA clusters.
// LDS row = 32 f16 = 4x16B chunks; swizzle ch ^= (row>>1)&3 (2-way only).
// gload_lds writes linearly -> global source chunk inverse-swizzled (rule 21).
// ---------------------------------------------------------------------------
__device__ __forceinline__ void stage32(
    const f16* __restrict__ src, int ld, f16* lds_slot, int tid)
{
    const int r0 = tid >> 2;      // 0..127
    const int cd = tid & 3;       // dest 16B chunk
#pragma unroll
    for (int p = 0; p < 2; ++p) {
        const int R = p * 128 + r0;
        const int gch = cd ^ ((R >> 1) & 3);             // inverse swizzle
        const f16* s = src + (size_t)R * ld + gch * 8;
        f16* d = lds_slot + (p * 128 + ((tid >> 6) << 4)) * 32;  // wave-uniform
        __builtin_amdgcn_global_load_lds((const AS1 uint32_t*)s,
                                         (AS3 uint32_t*)d, 16, 0, 0);
    }
}

template <int VM, bool STAGE>
__device__ __forceinline__ void tile_step(
    const f16* __restrict__ Ag, int lda,
    const f16* __restrict__ Bg, int ldb,
    f16* stA, f16* stB,
    const f16* cA, const f16* cB,
    int aoff, int boff,
    f32x4 (&acc)[8][4], int tid)
{
    asm volatile("s_waitcnt vmcnt(%0)" :: "n"(VM) : "memory");
    if (STAGE) stage32(Ag, lda, stA, tid);
    __builtin_amdgcn_s_barrier();
    f16x8 af[4], bf[4];
#pragma unroll
    for (int i = 0; i < 4; ++i) af[i] = *(const f16x8*)&cA[aoff + i * 512];
#pragma unroll
    for (int j = 0; j < 4; ++j) bf[j] = *(const f16x8*)&cB[boff + j * 512];
    __builtin_amdgcn_s_setprio(1);
#pragma unroll
    for (int i = 0; i < 4; ++i)
#pragma unroll
        for (int j = 0; j < 4; ++j)
            acc[i][j] = __builtin_amdgcn_mfma_f32_16x16x32_f16(af[i], bf[j], acc[i][j], 0, 0, 0);
    __builtin_amdgcn_s_setprio(0);
    __builtin_amdgcn_s_barrier();
    if (STAGE) stage32(Bg, ldb, stB, tid);
#pragma unroll
    for (int i = 0; i < 4; ++i) af[i] = *(const f16x8*)&cA[aoff + 2048 + i * 512];
    __builtin_amdgcn_s_setprio(1);
#pragma unroll
    for (int i = 0; i < 4; ++i)
#pragma unroll
        for (int j = 0; j < 4; ++j)
            acc[i + 4][j] = __builtin_amdgcn_mfma_f32_16x16x32_f16(af[i], bf[j], acc[i + 4][j], 0, 0, 0);
    __builtin_amdgcn_s_setprio(0);
    __builtin_amdgcn_s_barrier();
}

template <int T>
__device__ __forceinline__ void gemm256_v2(
    const f16* __restrict__ A, int lda,
    const f16* __restrict__ Bt, int ldb,
    f16 (*AsS)[256 * 32], f16 (*BsS)[256 * 32],
    f32x4 (&acc)[8][4], int tid)
{
    const int lane = tid & 63, w = tid >> 6;
    const int wr = w >> 2, wc = w & 3;
    const int cl = lane & 15, kg = lane >> 4;
    const int ch = kg ^ ((cl >> 1) & 3);     // constant per thread (rows == 0 mod 8)
    const int aoff = (wr * 128 + cl) * 32 + ch * 8;
    const int boff = (wc * 64 + cl) * 32 + ch * 8;

    // prologue: stage tiles 0,1,2 (order A0,B0,A1,B1,A2,B2 = 12 loads/thread)
#pragma unroll
    for (int t = 0; t < 3; ++t) {
        stage32(A + t * 32, lda, AsS[t], tid);
        stage32(Bt + t * 32, ldb, BsS[t], tid);
    }
#pragma unroll 1
    for (int t = 0; t < T - 3; ++t) {
        const int cs = t & 3, ss = (t + 3) & 3;
        tile_step<8, true>(A + (size_t)(t + 3) * 32, lda,
                           Bt + (size_t)(t + 3) * 32, ldb,
                           AsS[ss], BsS[ss], AsS[cs], BsS[cs],
                           aoff, boff, acc, tid);
    }
    // epilogue: drain 8 -> 4 -> 0
    tile_step<8, false>(A, lda, Bt, ldb, AsS[0], BsS[0],
                        AsS[(T - 3) & 3], BsS[(T - 3) & 3], aoff, boff, acc, tid);
    tile_step<4, false>(A, lda, Bt, ldb, AsS[0], BsS[0],
                        AsS[(T - 2) & 3], BsS[(T - 2) & 3], aoff, boff, acc, tid);
    tile_step<0, false>(A, lda, Bt, ldb, AsS[0], BsS[0],
                        AsS[(T - 1) & 3], BsS[(T - 1) & 3], aoff, boff, acc, tid);
}

// ---------------------------------------------------------------------------
// K1: Gp[s][b] = xT_b[:, s*2048 : +2048] self-product (full G, split-K=2).
// grid: 256 blocks (16 tiles x 8 batch x 2 splits), XCD-chunked swizzle.
// ---------------------------------------------------------------------------
__global__ __launch_bounds__(512, 2) void gemm_syk256(
    const f16* __restrict__ xT, f16* __restrict__ Gp)
{
    __shared__ f16 AsS[4][256 * 32];
    __shared__ f16 BsS[4][256 * 32];
    const int orig = blockIdx.x;
    const int l = (orig & 7) * 32 + (orig >> 3);   // 256 = 8*32, bijective
    const int tile = l & 15, b = (l >> 4) & 7, s = l >> 7;
    const int ti = tile >> 2, tj = tile & 3;

    const f16* base = xT + (size_t)b * (1024 * 4096) + (size_t)s * 2048;
    const f16* A  = base + (size_t)ti * 256 * 4096;
    const f16* Bt = base + (size_t)tj * 256 * 4096;

    f32x4 acc[8][4];
#pragma unroll
    for (int i = 0; i < 8; ++i)
#pragma unroll
        for (int j = 0; j < 4; ++j) acc[i][j] = f32x4{0.f, 0.f, 0.f, 0.f};

    gemm256_v2<64>(A, 4096, Bt, 4096, AsS, BsS, acc, threadIdx.x);

    f16* out = Gp + ((size_t)s * 8 + b) * 1048576;
    const int lane = threadIdx.x & 63, w = threadIdx.x >> 6;
    const int wr = w >> 2, wc = w & 3;
    const int cl = lane & 15, rg = lane >> 4;
#pragma unroll
    for (int i = 0; i < 8; ++i)
#pragma unroll
        for (int j = 0; j < 4; ++j)
#pragma unroll
            for (int q = 0; q < 4; ++q) {
                const int row = ti * 256 + wr * 128 + i * 16 + rg * 4 + q;
                const int col = tj * 256 + wc * 64 + j * 16 + cl;
                out[(size_t)row * 1024 + col] = (f16)acc[i][j][q];
            }
}

// ---------------------------------------------------------------------------
// reduce: G = Gp[0] + Gp[1]  (elementwise, f32 accumulate)
// ---------------------------------------------------------------------------
__global__ __launch_bounds__(256) void reduce_sum(
    const f16* __restrict__ Gp, f16* __restrict__ G)
{
    const size_t i = ((size_t)blockIdx.x * 256 + threadIdx.x) * 8;
    const f16x8 a = *(const f16x8*)(Gp + i);
    const f16x8 c = *(const f16x8*)(Gp + 8388608 + i);
    f16x8 o;
#pragma unroll
    for (int j = 0; j < 8; ++j) o[j] = (f16)((float)a[j] + (float)c[j]);
    *(f16x8*)(G + i) = o;
}

// ---------------------------------------------------------------------------
// K2 fused (256^2): UW2[b] = [Wq^T G_b ; Wv^T G_b], K=1024 (32 K-tiles).
// grid: 256 blocks (4 N x 8 M x 8 batch), XCD-chunked swizzle.
// ---------------------------------------------------------------------------
__global__ __launch_bounds__(512, 2) void gemm_qv256(
    const f16* __restrict__ WqkvT, const f16* __restrict__ G,
    f16* __restrict__ UW2)
{
    __shared__ f16 AsS[4][256 * 32];
    __shared__ f16 BsS[4][256 * 32];
    const int orig = blockIdx.x;
    const int l = (orig & 7) * 32 + (orig >> 3);
    const int bx = l & 3, by = (l >> 2) & 7, b = l >> 5;
    const int arow = (by < 4) ? by * 256 : 2048 + (by - 4) * 256;  // skip Wk

    const f16* A  = WqkvT + (size_t)arow * 1024;
    const f16* Bt = G + (size_t)b * 1048576 + (size_t)bx * 256 * 1024;

    f32x4 acc[8][4];
#pragma unroll
    for (int i = 0; i < 8; ++i)
#pragma unroll
        for (int j = 0; j < 4; ++j) acc[i][j] = f32x4{0.f, 0.f, 0.f, 0.f};

    gemm256_v2<32>(A, 1024, Bt, 1024, AsS, BsS, acc, threadIdx.x);

    f16* C = UW2 + (size_t)b * 2097152;
    const int lane = threadIdx.x & 63, w = threadIdx.x >> 6;
    const int wr = w >> 2, wc = w & 3;
    const int cl = lane & 15, rg = lane >> 4;
#pragma unroll
    for (int i = 0; i < 8; ++i)
#pragma unroll
        for (int j = 0; j < 4; ++j) {
            const int cc = bx * 256 + wc * 64 + j * 16 + cl;
#pragma unroll
            for (int q = 0; q < 4; ++q) {
                const int rr = by * 256 + wr * 128 + i * 16 + rg * 4 + q;
                C[(size_t)rr * 1024 + cc] = (f16)acc[i][j][q];
            }
        }
}

// ---------------------------------------------------------------------------
// Legacy 128x128 body (used by gemm_out only)
// ---------------------------------------------------------------------------
__device__ __forceinline__ void gemm_body(
    const f16* __restrict__ A, const f16* __restrict__ Bt,
    int lda, int ldb, int K, f16* As, f16* Bs,
    f32x4 (&acc)[4][4], int tid)
{
    const int lane = tid & 63, w = tid >> 6;
    const int wr = w >> 1, wc = w & 1;
    const int lrow = lane >> 3;
    const int lcol = (lane & 7) * 8;
    for (int k0 = 0; k0 < K; k0 += 64) {
#pragma unroll
        for (int p = 0; p < 4; ++p) {
            const f16* sa = A + (size_t)(p * 32 + w * 8 + lrow) * lda + k0 + lcol;
            __builtin_amdgcn_global_load_lds(
                (const AS1 uint32_t*)sa,
                (AS3 uint32_t*)((char*)As + p * 4096 + w * 1024), 16, 0, 0);
            const f16* sb = Bt + (size_t)(p * 32 + w * 8 + lrow) * ldb + k0 + lcol;
            __builtin_amdgcn_global_load_lds(
                (const AS1 uint32_t*)sb,
                (AS3 uint32_t*)((char*)Bs + p * 4096 + w * 1024), 16, 0, 0);
        }
        __syncthreads();
#pragma unroll
        for (int kk = 0; kk < 2; ++kk) {
            f16x8 af[4], bfr[4];
#pragma unroll
            for (int i = 0; i < 4; ++i)
                af[i] = *(const f16x8*)&As[(wr * 64 + i * 16 + (lane & 15)) * 64 + kk * 32 + (lane >> 4) * 8];
#pragma unroll
            for (int j = 0; j < 4; ++j)
                bfr[j] = *(const f16x8*)&Bs[(wc * 64 + j * 16 + (lane & 15)) * 64 + kk * 32 + (lane >> 4) * 8];
#pragma unroll
            for (int i = 0; i < 4; ++i)
#pragma unroll
                for (int j = 0; j < 4; ++j)
                    acc[i][j] = __builtin_amdgcn_mfma_f32_16x16x32_f16(af[i], bfr[j], acc[i][j], 0, 0, 0);
        }
        __syncthreads();
    }
}

// ---------------------------------------------------------------------------
// bias_init: d_out[512][1024] = bias row-broadcast
// ---------------------------------------------------------------------------
__global__ __launch_bounds__(256) void bias_init(
    const float* __restrict__ bias, float* __restrict__ out)
{
    const int idx = blockIdx.x * 1024 + threadIdx.x * 4;
    const float4 bv = *(const float4*)(bias + (idx & 1023));
    *(float4*)(out + idx) = bv;
}

// ---------------------------------------------------------------------------
// K4: d_out += A * Bt^T, split-K=2 via f32 atomics. grid (8,4,2)
// ---------------------------------------------------------------------------
__global__ __launch_bounds__(256) void gemm_out(
    const f16* __restrict__ A, const f16* __restrict__ Bt,
    float* __restrict__ Cout)
{
    __shared__ f16 As[128 * 64];
    __shared__ f16 Bs[128 * 64];
    const int tn0 = blockIdx.x * 128;
    const int tm0 = blockIdx.y * 128;
    const int s = blockIdx.z;
    f32x4 acc[4][4];
#pragma unroll
    for (int i = 0; i < 4; ++i)
#pragma unroll
        for (int j = 0; j < 4; ++j) acc[i][j] = f32x4{0.f, 0.f, 0.f, 0.f};

    gemm_body(A + (size_t)tm0 * 1024 + s * 512,
              Bt + (size_t)tn0 * 1024 + s * 512, 1024, 1024, 512,
              As, Bs, acc, threadIdx.x);

    const int lane = threadIdx.x & 63, w = threadIdx.x >> 6;
    const int wr = w >> 1, wc = w & 1;
    const int cl = lane & 15, rg = lane >> 4;
#pragma unroll
    for (int i = 0; i < 4; ++i)
#pragma unroll
        for (int j = 0; j < 4; ++j) {
            const int cc = tn0 + wc * 64 + j * 16 + cl;
#pragma unroll
            for (int q = 0; q < 4; ++q) {
                const int rr = tm0 + wr * 64 + i * 16 + rg * 4 + q;
                atomicAdd(&Cout[(size_t)rr * 1024 + cc], acc[i][j][q]);
            }
        }
}

// ---------------------------------------------------------------------------
// Per (b,h): dots = U_h * Wk_h^T, vv = W2_h * Wv2_h^T  (64x64, K=1024),
// softmax(dots*0.125), out = attn @ vv -> O (f16)
// grid: (16 heads, 8 batches), block 512 (8 waves)
// ---------------------------------------------------------------------------
__global__ __launch_bounds__(512) void attn_small(
    const f16* __restrict__ UW2, const f16* __restrict__ WqkvT,
    f16* __restrict__ O)
{
    __shared__ float dots[64][66];
    __shared__ float vv[64][66];
    const int h = blockIdx.x, b = blockIdx.y;
    const int tid = threadIdx.x, lane = tid & 63, w = tid >> 6;
    const int isVV = w >> 2;
    const int kq = w & 3;

    const f16* Arows = UW2 + (size_t)b * (2048 * 1024)
                           + (size_t)isVV * (1024 * 1024) + (size_t)h * 64 * 1024;
    const f16* Brows = WqkvT + (size_t)(isVV ? 3072 : 1024) * 1024 + (size_t)h * 64 * 1024;

    f32x4 acc[4][4];
#pragma unroll
    for (int i = 0; i < 4; ++i)
#pragma unroll
        for (int j = 0; j < 4; ++j) acc[i][j] = f32x4{0.f, 0.f, 0.f, 0.f};

    const int cl = lane & 15, kg = lane >> 4;
    for (int ks = 0; ks < 8; ++ks) {
        const int k0 = kq * 256 + ks * 32 + kg * 8;
        f16x8 af[4], bfr[4];
#pragma unroll
        for (int i = 0; i < 4; ++i)
            af[i] = *(const f16x8*)(Arows + (size_t)(i * 16 + cl) * 1024 + k0);
#pragma unroll
        for (int j = 0; j < 4; ++j)
            bfr[j] = *(const f16x8*)(Brows + (size_t)(j * 16 + cl) * 1024 + k0);
#pragma unroll
        for (int i = 0; i < 4; ++i)
#pragma unroll
            for (int j = 0; j < 4; ++j)
                acc[i][j] = __builtin_amdgcn_mfma_f32_16x16x32_f16(af[i], bfr[j], acc[i][j], 0, 0, 0);
    }

    float (*dst)[66] = isVV ? vv : dots;
#pragma unroll
    for (int r = 0; r < 4; ++r) {
        if (kq == r) {
            if (r == 0) {
#pragma unroll
                for (int i = 0; i < 4; ++i)
#pragma unroll
                    for (int j = 0; j < 4; ++j)
#pragma unroll
                        for (int q = 0; q < 4; ++q)
                            dst[i * 16 + kg * 4 + q][j * 16 + cl] = acc[i][j][q];
            } else {
#pragma unroll
                for (int i = 0; i < 4; ++i)
#pragma unroll
                    for (int j = 0; j < 4; ++j)
#pragma unroll
                        for (int q = 0; q < 4; ++q)
                            dst[i * 16 + kg * 4 + q][j * 16 + cl] += acc[i][j][q];
            }
        }
        __syncthreads();
    }

    if (tid < 64) {
        const int r = tid;
        float mx = -1e30f;
        for (int e = 0; e < 64; ++e) {
            const float v = dots[r][e] * 0.125f;
            dots[r][e] = v;
            mx = fmaxf(mx, v);
        }
        float s = 0.f;
        for (int e = 0; e < 64; ++e) {
            const float v = __expf(dots[r][e] - mx);
            dots[r][e] = v;
            s += v;
        }
        const float inv = 1.f / s;
        for (int e = 0; e < 64; ++e) dots[r][e] *= inv;
    }
    __syncthreads();

    {
        const int r = tid >> 3, f0 = (tid & 7) * 8;
        float o[8];
#pragma unroll
        for (int i = 0; i < 8; ++i) o[i] = 0.f;
        for (int e = 0; e < 64; ++e) {
            const float a = dots[r][e];
#pragma unroll
            for (int i = 0; i < 8; ++i) o[i] += a * vv[e][f0 + i];
        }
        f16* Od = O + (size_t)b * 64 * 1024 + (size_t)r * 1024 + h * 64 + f0;
#pragma unroll
        for (int i = 0; i < 8; ++i) Od[i] = (f16)o[i];
    }
}

// ---------------------------------------------------------------------------
extern "C" void kernel_launch(void* const* d_in, const int* in_sizes, int n_in,
                              void* d_out, int out_size, void* d_ws, size_t ws_size,
                              hipStream_t stream)
{
    const float* x    = (const float*)d_in[0];  // [8][4096][1024]
    const float* Wqkv = (const float*)d_in[1];  // [1024][4096]
    const float* Wout = (const float*)d_in[2];  // [1024][1024]
    const float* bout = (const float*)d_in[3];  // [1024]

    char* ws = (char*)d_ws;
    f16* xT    = (f16*)(ws + 0);           // [8][1024][4096]   67108864 B
    f16* WqkvT = (f16*)(ws + 67108864);    // [4096][1024]       8388608 B
    f16* WoutT = (f16*)(ws + 75497472);    // [1024][1024]       2097152 B
    f16* G     = (f16*)(ws + 77594624);    // [8][1024][1024]   16777216 B
    f16* Gp    = (f16*)(ws + 94371840);    // [2][8][1024][1024] 33554432 B
    f16* UW2   = (f16*)(ws + 94371840);    // union w/ Gp (qv runs after reduce)
    f16* O     = (f16*)(ws + 127926272);   // [8][64][1024]      1048576 B

    tr_cvt_kernel<<<dim3(16, 64, 8), 256, 0, stream>>>(x, xT, 4096, 1024);
    tr_cvt_kernel<<<dim3(64, 16, 1), 256, 0, stream>>>(Wqkv, WqkvT, 1024, 4096);
    tr_cvt_kernel<<<dim3(16, 16, 1), 256, 0, stream>>>(Wout, WoutT, 1024, 1024);

    // K1: full-G split-K=2, 256^2 tiles, deep-pipelined BK=32 ring
    gemm_syk256<<<256, 512, 0, stream>>>(xT, Gp);
    // G = Gp0 + Gp1
    reduce_sum<<<4096, 256, 0, stream>>>(Gp, G);
    // K2 fused: UW2 = [Wq^T G ; Wv^T G]
    gemm_qv256<<<256, 512, 0, stream>>>(WqkvT, G, UW2);
    // K3: per (b,h) small attention
    attn_small<<<dim3(16, 8), 512, 0, stream>>>(UW2, WqkvT, O);
    // K4: out = bias ; out += O @ WoutT^T (split-K=2, f32 atomics)
    bias_init<<<512, 256, 0, stream>>>(bout, (float*)d_out);
    gemm_out<<<dim3(8, 4, 2), 256, 0, stream>>>(O, WoutT, (float*)d_out);
}